// Round 5
// baseline (141.894 us; speedup 1.0000x reference)
//
#include <hip/hip_runtime.h>

typedef __attribute__((ext_vector_type(8))) short short8;
typedef __attribute__((ext_vector_type(4))) short short4v;
typedef __attribute__((ext_vector_type(4))) float f32x4;
typedef unsigned int uint32;
typedef unsigned short ushort_t;

#define NBATCH 4096
#define GRID   768

// LDS layout (bytes). All bf16 tiles, 128B row stride, XOR-swizzled. 48 KB.
#define LDS_FB0  0u        // F buffer 0 [128][64]
#define LDS_FB1  16384u    // F buffer 1 [128][64]
#define LDS_GHT  32768u    // G, then HT in-place [64][64]
#define LDS_KB   40960u    // Kw [64][64] row-major

__device__ __forceinline__ uint32 swzb(uint32 base, uint32 row, uint32 colByte) {
    return (base + row * 128u + colByte) ^ ((row & 7u) << 4);
}
__device__ __forceinline__ uint32 pk2(float lo, float hi) {   // v_cvt_pk_bf16_f32 (RNE)
    uint32 r;
    asm("v_cvt_pk_bf16_f32 %0, %1, %2" : "=v"(r) : "v"(lo), "v"(hi));
    return r;
}
__device__ __forceinline__ ushort_t bfbits(float x) {         // RNE f32 -> bf16 bits
    uint32 u = __float_as_uint(x);
    return (ushort_t)((u + 0x7FFFu + ((u >> 16) & 1u)) >> 16);
}
__device__ __forceinline__ float bf2f(ushort_t b) {
    return __uint_as_float(((uint32)b) << 16);
}
__device__ __forceinline__ short4v tr16(uint32 addr) {        // ds_read_b64_tr_b16
    short4v d;
    asm volatile("ds_read_b64_tr_b16 %0, %1" : "=v"(d) : "v"(addr));
    return d;
}
#define CAT8(lo, hi) __builtin_shufflevector(lo, hi, 0, 1, 2, 3, 4, 5, 6, 7)
#define MFMA(a, b, c) __builtin_amdgcn_mfma_f32_16x16x32_bf16((a), (b), (c), 0, 0, 0)

// Issue 10 transpose-reads for one K-chunk kk of G = F^T F.
#define G_ISSUE(kk, al, ah, b0l, b0h, b1l, b1h, b2l, b2h, b3l, b3h) do {       \
    uint32 rA = (uint32)(32 * (kk)) + 8u * kq + trr;                           \
    al  = tr16(ldsb + swzb(fbCur, rA,      wc  + trc));                        \
    ah  = tr16(ldsb + swzb(fbCur, rA + 4u, wc  + trc));                        \
    b0l = tr16(ldsb + swzb(fbCur, rA,      0u  + trc));                        \
    b0h = tr16(ldsb + swzb(fbCur, rA + 4u, 0u  + trc));                        \
    b1l = tr16(ldsb + swzb(fbCur, rA,      32u + trc));                        \
    b1h = tr16(ldsb + swzb(fbCur, rA + 4u, 32u + trc));                        \
    b2l = tr16(ldsb + swzb(fbCur, rA,      64u + trc));                        \
    b2h = tr16(ldsb + swzb(fbCur, rA + 4u, 64u + trc));                        \
    b3l = tr16(ldsb + swzb(fbCur, rA,      96u + trc));                        \
    b3h = tr16(ldsb + swzb(fbCur, rA + 4u, 96u + trc));                        \
} while (0)

#define G_MFMA(al, ah, b0l, b0h, b1l, b1h, b2l, b2h, b3l, b3h) do {            \
    short8 a_ = CAT8(al, ah);                                                  \
    accG[0] = MFMA(a_, CAT8(b0l, b0h), accG[0]);                               \
    accG[1] = MFMA(a_, CAT8(b1l, b1h), accG[1]);                               \
    accG[2] = MFMA(a_, CAT8(b2l, b2h), accG[2]);                               \
    accG[3] = MFMA(a_, CAT8(b3l, b3h), accG[3]);                               \
} while (0)

#define WAIT_LGKM(n) do {                                                      \
    asm volatile("s_waitcnt lgkmcnt(" #n ")" ::: "memory");                    \
    __builtin_amdgcn_sched_barrier(0);                                         \
} while (0)

__global__ __launch_bounds__(256, 3)
void sam3e_kernel(const float* __restrict__ F,
                  const float* __restrict__ Kw,
                  const float* __restrict__ Qw,
                  float* __restrict__ out) {
    __shared__ __align__(128) unsigned char smem[49152];
    const uint32 ldsb = (uint32)(size_t)(void*)smem;
    const int t    = threadIdx.x;
    const int lane = t & 63;
    const int wave = t >> 6;
    const uint32 r16 = (uint32)(lane & 15);
    const uint32 kq  = (uint32)(lane >> 4);
    const uint32 wc  = 32u * (uint32)wave;
    const uint32 trc = 8u * (r16 & 3u);
    const uint32 trr = r16 >> 2;
    const int n0 = t >> 4;               // F-stage row base
    const int c4 = (t & 15) * 4;         // F-stage float col

    // ---- once per block: Kw -> LDS
    #pragma unroll
    for (int i = 0; i < 4; ++i) {
        int idx4 = t + 256 * i;
        uint32 r = (uint32)(idx4 >> 4);
        uint32 cB = (uint32)((idx4 & 15) * 8);
        float4 vk = *(const float4*)(Kw + 4 * idx4);
        uint2 pk; pk.x = pk2(vk.x, vk.y); pk.y = pk2(vk.z, vk.w);
        *(uint2*)(smem + swzb(LDS_KB, r, cB)) = pk;
    }
    // ---- once per block: Qw B-fragments -> regs
    short8 qf[2][4];
    #pragma unroll
    for (int kk = 0; kk < 2; ++kk)
        #pragma unroll
        for (int tn = 0; tn < 4; ++tn) {
            const float* qp = Qw + (16 * tn + (int)r16) * 64 + 32 * kk + 8 * (int)kq;
            float4 u0 = *(const float4*)(qp);
            float4 u1 = *(const float4*)(qp + 4);
            union { short8 s; uint32 u[4]; } cv;
            cv.u[0] = pk2(u0.x, u0.y); cv.u[1] = pk2(u0.z, u0.w);
            cv.u[2] = pk2(u1.x, u1.y); cv.u[3] = pk2(u1.z, u1.w);
            qf[kk][tn] = cv.s;
        }

    // ---- stage first batch's F into FB0
    const int bx = blockIdx.x;
    {
        const float* Fg = F + (size_t)bx * 8192;
        #pragma unroll
        for (int i = 0; i < 8; ++i) {
            int n = n0 + 16 * i;
            float4 v = *(const float4*)(Fg + n * 64 + c4);
            uint2 pk; pk.x = pk2(v.x, v.y); pk.y = pk2(v.z, v.w);
            *(uint2*)(smem + swzb(LDS_FB0, (uint32)n, (uint32)(2 * c4))) = pk;
        }
    }
    __syncthreads();

    uint32 fbCur = LDS_FB0, fbNxt = LDS_FB1;
    for (int batch = bx; batch < NBATCH; batch += GRID) {
        const bool hasNext = (batch + GRID) < NBATCH;
        const float* Fn = F + (size_t)(batch + GRID) * 8192;
        float4 pf[8];
        if (hasNext) {                       // prefetch first half
            #pragma unroll
            for (int i = 0; i < 4; ++i)
                pf[i] = *(const float4*)(Fn + (n0 + 16 * i) * 64 + c4);
        }
        __builtin_amdgcn_sched_barrier(0);   // keep loads above the counted-wait region

        // ---- G = F^T F (64x64, K=128), 2-deep pipelined tr-reads
        f32x4 accG[4];
        #pragma unroll
        for (int i = 0; i < 4; ++i) accG[i] = (f32x4){0.f, 0.f, 0.f, 0.f};
        {
            short4v xal, xah, xb0l, xb0h, xb1l, xb1h, xb2l, xb2h, xb3l, xb3h;
            short4v yal, yah, yb0l, yb0h, yb1l, yb1h, yb2l, yb2h, yb3l, yb3h;
            G_ISSUE(0, xal, xah, xb0l, xb0h, xb1l, xb1h, xb2l, xb2h, xb3l, xb3h);
            G_ISSUE(1, yal, yah, yb0l, yb0h, yb1l, yb1h, yb2l, yb2h, yb3l, yb3h);
            WAIT_LGKM(10);
            G_MFMA(xal, xah, xb0l, xb0h, xb1l, xb1h, xb2l, xb2h, xb3l, xb3h);
            G_ISSUE(2, xal, xah, xb0l, xb0h, xb1l, xb1h, xb2l, xb2h, xb3l, xb3h);
            WAIT_LGKM(10);
            G_MFMA(yal, yah, yb0l, yb0h, yb1l, yb1h, yb2l, yb2h, yb3l, yb3h);
            G_ISSUE(3, yal, yah, yb0l, yb0h, yb1l, yb1h, yb2l, yb2h, yb3l, yb3h);
            WAIT_LGKM(10);
            G_MFMA(xal, xah, xb0l, xb0h, xb1l, xb1h, xb2l, xb2h, xb3l, xb3h);
            WAIT_LGKM(0);
            G_MFMA(yal, yah, yb0l, yb0h, yb1l, yb1h, yb2l, yb2h, yb3l, yb3h);
        }
        // write G band w (wave-local rows)
        #pragma unroll
        for (int tn = 0; tn < 4; ++tn)
            #pragma unroll
            for (int r = 0; r < 4; ++r)
                *(ushort_t*)(smem + swzb(LDS_GHT, 16u * (uint32)wave + 4u * kq + (uint32)r,
                                         32u * (uint32)tn + 2u * r16)) = bfbits(accG[tn][r]);
        asm volatile("s_waitcnt lgkmcnt(0)" ::: "memory");
        __builtin_amdgcn_sched_barrier(0);

        if (hasNext) {                       // prefetch second half
            #pragma unroll
            for (int i = 4; i < 8; ++i)
                pf[i] = *(const float4*)(Fn + (n0 + 16 * i) * 64 + c4);
        }

        // ---- HT = G @ Kw^T (64x64, K=64), band w in-place over G band w
        f32x4 accH[4];
        #pragma unroll
        for (int i = 0; i < 4; ++i) accH[i] = (f32x4){0.f, 0.f, 0.f, 0.f};
        #pragma unroll
        for (int kk = 0; kk < 2; ++kk) {
            uint32 cb = 64u * (uint32)kk + 16u * kq;
            short8 a = *(const short8*)(smem + swzb(LDS_GHT, 16u * (uint32)wave + r16, cb));
            #pragma unroll
            for (int tn = 0; tn < 4; ++tn) {
                short8 bb = *(const short8*)(smem + swzb(LDS_KB, 16u * (uint32)tn + r16, cb));
                accH[tn] = MFMA(a, bb, accH[tn]);
            }
        }
        asm volatile("" ::: "memory");
        #pragma unroll
        for (int tn = 0; tn < 4; ++tn)
            #pragma unroll
            for (int r = 0; r < 4; ++r)
                *(ushort_t*)(smem + swzb(LDS_GHT, 16u * (uint32)wave + 4u * kq + (uint32)r,
                                         32u * (uint32)tn + 2u * r16)) = bfbits(accH[tn][r]);
        __syncthreads();

        // ---- consume prefetch: cvt + write next F buffer (overlaps nothing it depends on)
        if (hasNext) {
            #pragma unroll
            for (int i = 0; i < 8; ++i) {
                int n = n0 + 16 * i;
                uint2 pk; pk.x = pk2(pf[i].x, pf[i].y); pk.y = pk2(pf[i].z, pf[i].w);
                *(uint2*)(smem + swzb(fbNxt, (uint32)n, (uint32)(2 * c4))) = pk;
            }
        }

        // ---- T = F @ H, QF = F @ Qw^T (128x64, K=64)
        f32x4 accT[2][4], accQ[2][4];
        #pragma unroll
        for (int i = 0; i < 2; ++i)
            #pragma unroll
            for (int j = 0; j < 4; ++j) {
                accT[i][j] = (f32x4){0.f, 0.f, 0.f, 0.f};
                accQ[i][j] = (f32x4){0.f, 0.f, 0.f, 0.f};
            }
        #pragma unroll
        for (int kk = 0; kk < 2; ++kk) {
            uint32 cb = 64u * (uint32)kk + 16u * kq;
            short8 a0 = *(const short8*)(smem + swzb(fbCur, 16u * (uint32)(2 * wave + 0) + r16, cb));
            short8 a1 = *(const short8*)(smem + swzb(fbCur, 16u * (uint32)(2 * wave + 1) + r16, cb));
            #pragma unroll
            for (int tn = 0; tn < 4; ++tn) {
                short8 bt = *(const short8*)(smem + swzb(LDS_GHT, 16u * (uint32)tn + r16, cb));
                accT[0][tn] = MFMA(a0, bt, accT[0][tn]);
                accQ[0][tn] = MFMA(a0, qf[kk][tn], accQ[0][tn]);
                accT[1][tn] = MFMA(a1, bt, accT[1][tn]);
                accQ[1][tn] = MFMA(a1, qf[kk][tn], accQ[1][tn]);
            }
        }

        // ---- epilogue: out = F .* T + QF
        float* og = out + (size_t)batch * 8192;
        #pragma unroll
        for (int i2 = 0; i2 < 2; ++i2)
            #pragma unroll
            for (int tn = 0; tn < 4; ++tn)
                #pragma unroll
                for (int r = 0; r < 4; ++r) {
                    uint32 n = 16u * (uint32)(2 * wave + i2) + 4u * kq + (uint32)r;
                    uint32 d = 16u * (uint32)tn + r16;
                    float f = bf2f(*(const ushort_t*)(smem + swzb(fbCur, n, 2u * d)));
                    og[n * 64 + d] = fmaf(f, accT[i2][tn][r], accQ[i2][tn][r]);
                }
        __syncthreads();
        uint32 tmp = fbCur; fbCur = fbNxt; fbNxt = tmp;
    }
}

extern "C" void kernel_launch(void* const* d_in, const int* in_sizes, int n_in,
                              void* d_out, int out_size, void* d_ws, size_t ws_size,
                              hipStream_t stream) {
    const float* F  = (const float*)d_in[0];
    const float* Kw = (const float*)d_in[1];
    const float* Qw = (const float*)d_in[2];
    float* out = (float*)d_out;
    sam3e_kernel<<<dim3(GRID), dim3(256), 0, stream>>>(F, Kw, Qw, out);
}

// Round 6
// 54.637 us; speedup vs baseline: 2.5970x; 2.5970x over previous
//
#include <hip/hip_runtime.h>

typedef __attribute__((ext_vector_type(8))) short short8;
typedef __attribute__((ext_vector_type(4))) short short4v;
typedef __attribute__((ext_vector_type(4))) float f32x4;
typedef unsigned int uint32;
typedef unsigned short ushort_t;

// LDS layout (bytes). All bf16 tiles, 128B row stride, XOR-swizzled. 32 KB.
#define LDS_FB   0u        // F   [128][64]
#define LDS_GHT  16384u    // G, then HT in-place [64][64]
#define LDS_KB   24576u    // Kw  [64][64] row-major

__device__ __forceinline__ uint32 swzb(uint32 base, uint32 row, uint32 colByte) {
    return (base + row * 128u + colByte) ^ ((row & 7u) << 4);
}
__device__ __forceinline__ uint32 pk2(float lo, float hi) {   // v_cvt_pk_bf16_f32 (RNE)
    uint32 r;
    asm("v_cvt_pk_bf16_f32 %0, %1, %2" : "=v"(r) : "v"(lo), "v"(hi));
    return r;
}
__device__ __forceinline__ ushort_t bfbits(float x) {         // RNE f32 -> bf16 bits
    uint32 u = __float_as_uint(x);
    return (ushort_t)((u + 0x7FFFu + ((u >> 16) & 1u)) >> 16);
}
__device__ __forceinline__ float bf2f(ushort_t b) {
    return __uint_as_float(((uint32)b) << 16);
}
__device__ __forceinline__ short4v tr16(uint32 addr) {        // ds_read_b64_tr_b16
    short4v d;
    asm volatile("ds_read_b64_tr_b16 %0, %1" : "=v"(d) : "v"(addr));
    return d;
}
#define CAT8(lo, hi) __builtin_shufflevector(lo, hi, 0, 1, 2, 3, 4, 5, 6, 7)
#define MFMA(a, b, c) __builtin_amdgcn_mfma_f32_16x16x32_bf16((a), (b), (c), 0, 0, 0)

// Issue 10 transpose-reads for one K-chunk kk of G = F^T F.
#define G_ISSUE(kk, al, ah, b0l, b0h, b1l, b1h, b2l, b2h, b3l, b3h) do {       \
    uint32 rA = (uint32)(32 * (kk)) + 8u * kq + trr;                           \
    al  = tr16(ldsb + swzb(LDS_FB, rA,      wc  + trc));                       \
    ah  = tr16(ldsb + swzb(LDS_FB, rA + 4u, wc  + trc));                       \
    b0l = tr16(ldsb + swzb(LDS_FB, rA,      0u  + trc));                       \
    b0h = tr16(ldsb + swzb(LDS_FB, rA + 4u, 0u  + trc));                       \
    b1l = tr16(ldsb + swzb(LDS_FB, rA,      32u + trc));                       \
    b1h = tr16(ldsb + swzb(LDS_FB, rA + 4u, 32u + trc));                       \
    b2l = tr16(ldsb + swzb(LDS_FB, rA,      64u + trc));                       \
    b2h = tr16(ldsb + swzb(LDS_FB, rA + 4u, 64u + trc));                       \
    b3l = tr16(ldsb + swzb(LDS_FB, rA,      96u + trc));                       \
    b3h = tr16(ldsb + swzb(LDS_FB, rA + 4u, 96u + trc));                       \
} while (0)

#define G_MFMA(al, ah, b0l, b0h, b1l, b1h, b2l, b2h, b3l, b3h) do {            \
    short8 a_ = CAT8(al, ah);                                                  \
    accG[0] = MFMA(a_, CAT8(b0l, b0h), accG[0]);                               \
    accG[1] = MFMA(a_, CAT8(b1l, b1h), accG[1]);                               \
    accG[2] = MFMA(a_, CAT8(b2l, b2h), accG[2]);                               \
    accG[3] = MFMA(a_, CAT8(b3l, b3h), accG[3]);                               \
} while (0)

#define WAIT_LGKM(n) do {                                                      \
    asm volatile("s_waitcnt lgkmcnt(" #n ")" ::: "memory");                    \
    __builtin_amdgcn_sched_barrier(0);                                         \
} while (0)

__global__ __launch_bounds__(256, 4)
void sam3e_kernel(const float* __restrict__ F,
                  const float* __restrict__ Kw,
                  const float* __restrict__ Qw,
                  float* __restrict__ out) {
    __shared__ __align__(128) unsigned char smem[32768];
    const uint32 ldsb = (uint32)(size_t)(void*)smem;
    const int t    = threadIdx.x;
    const int lane = t & 63;
    const int wave = t >> 6;
    const int b    = blockIdx.x;
    const uint32 r16 = (uint32)(lane & 15);
    const uint32 kq  = (uint32)(lane >> 4);
    const uint32 wc  = 32u * (uint32)wave;
    const uint32 trc = 8u * (r16 & 3u);
    const uint32 trr = r16 >> 2;

    // ---- stage F (batch b) -> bf16 LDS, row-major (HW cvt_pk)
    const float* Fg = F + (size_t)b * 8192;
    {
        int n0 = t >> 4;
        int c4 = (t & 15) * 4;
        #pragma unroll
        for (int i = 0; i < 8; ++i) {
            int n = n0 + 16 * i;
            float4 v = *(const float4*)(Fg + n * 64 + c4);
            uint2 pk; pk.x = pk2(v.x, v.y); pk.y = pk2(v.z, v.w);
            *(uint2*)(smem + swzb(LDS_FB, (uint32)n, (uint32)(2 * c4))) = pk;
        }
    }
    // ---- stage Kw -> LDS (1024 float4s across 256 threads)
    #pragma unroll
    for (int i = 0; i < 4; ++i) {
        int idx4 = t + 256 * i;
        uint32 r = (uint32)(idx4 >> 4);
        uint32 cB = (uint32)((idx4 & 15) * 8);
        float4 vk = *(const float4*)(Kw + 4 * idx4);
        uint2 pk; pk.x = pk2(vk.x, vk.y); pk.y = pk2(vk.z, vk.w);
        *(uint2*)(smem + swzb(LDS_KB, r, cB)) = pk;
    }
    // ---- Qw B-fragments -> regs (L2-served after first blocks)
    short8 qf[2][4];
    #pragma unroll
    for (int kk = 0; kk < 2; ++kk)
        #pragma unroll
        for (int tn = 0; tn < 4; ++tn) {
            const float* qp = Qw + (16 * tn + (int)r16) * 64 + 32 * kk + 8 * (int)kq;
            float4 u0 = *(const float4*)(qp);
            float4 u1 = *(const float4*)(qp + 4);
            union { short8 s; uint32 u[4]; } cv;
            cv.u[0] = pk2(u0.x, u0.y); cv.u[1] = pk2(u0.z, u0.w);
            cv.u[2] = pk2(u1.x, u1.y); cv.u[3] = pk2(u1.z, u1.w);
            qf[kk][tn] = cv.s;
        }
    __syncthreads();

    // ---- G = F^T F (64x64, K=128), 2-deep pipelined transpose-reads
    f32x4 accG[4];
    #pragma unroll
    for (int i = 0; i < 4; ++i) accG[i] = (f32x4){0.f, 0.f, 0.f, 0.f};
    {
        short4v xal, xah, xb0l, xb0h, xb1l, xb1h, xb2l, xb2h, xb3l, xb3h;
        short4v yal, yah, yb0l, yb0h, yb1l, yb1h, yb2l, yb2h, yb3l, yb3h;
        G_ISSUE(0, xal, xah, xb0l, xb0h, xb1l, xb1h, xb2l, xb2h, xb3l, xb3h);
        G_ISSUE(1, yal, yah, yb0l, yb0h, yb1l, yb1h, yb2l, yb2h, yb3l, yb3h);
        WAIT_LGKM(10);
        G_MFMA(xal, xah, xb0l, xb0h, xb1l, xb1h, xb2l, xb2h, xb3l, xb3h);
        G_ISSUE(2, xal, xah, xb0l, xb0h, xb1l, xb1h, xb2l, xb2h, xb3l, xb3h);
        WAIT_LGKM(10);
        G_MFMA(yal, yah, yb0l, yb0h, yb1l, yb1h, yb2l, yb2h, yb3l, yb3h);
        G_ISSUE(3, yal, yah, yb0l, yb0h, yb1l, yb1h, yb2l, yb2h, yb3l, yb3h);
        WAIT_LGKM(10);
        G_MFMA(xal, xah, xb0l, xb0h, xb1l, xb1h, xb2l, xb2h, xb3l, xb3h);
        WAIT_LGKM(0);
        G_MFMA(yal, yah, yb0l, yb0h, yb1l, yb1h, yb2l, yb2h, yb3l, yb3h);
    }
    // write G band w (wave-local rows: only this wave reads them back)
    #pragma unroll
    for (int tn = 0; tn < 4; ++tn)
        #pragma unroll
        for (int r = 0; r < 4; ++r)
            *(ushort_t*)(smem + swzb(LDS_GHT, 16u * (uint32)wave + 4u * kq + (uint32)r,
                                     32u * (uint32)tn + 2u * r16)) = bfbits(accG[tn][r]);
    asm volatile("s_waitcnt lgkmcnt(0)" ::: "memory");  // wave-local RAW on GHT band
    __builtin_amdgcn_sched_barrier(0);

    // ---- HT = G @ Kw^T (64x64, K=64), band w in-place over G band w
    f32x4 accH[4];
    #pragma unroll
    for (int i = 0; i < 4; ++i) accH[i] = (f32x4){0.f, 0.f, 0.f, 0.f};
    #pragma unroll
    for (int kk = 0; kk < 2; ++kk) {
        uint32 cb = 64u * (uint32)kk + 16u * kq;
        short8 a = *(const short8*)(smem + swzb(LDS_GHT, 16u * (uint32)wave + r16, cb));
        #pragma unroll
        for (int tn = 0; tn < 4; ++tn) {
            short8 bb = *(const short8*)(smem + swzb(LDS_KB, 16u * (uint32)tn + r16, cb));
            accH[tn] = MFMA(a, bb, accH[tn]);
        }
    }
    asm volatile("" ::: "memory");  // keep HT stores below G reads
    #pragma unroll
    for (int tn = 0; tn < 4; ++tn)
        #pragma unroll
        for (int r = 0; r < 4; ++r)
            *(ushort_t*)(smem + swzb(LDS_GHT, 16u * (uint32)wave + 4u * kq + (uint32)r,
                                     32u * (uint32)tn + 2u * r16)) = bfbits(accH[tn][r]);
    __syncthreads();

    // ---- T = F @ H (B from HT rows), QF = F @ Qw^T (B from qf regs). 128x64, K=64.
    f32x4 accT[2][4], accQ[2][4];
    #pragma unroll
    for (int i = 0; i < 2; ++i)
        #pragma unroll
        for (int j = 0; j < 4; ++j) {
            accT[i][j] = (f32x4){0.f, 0.f, 0.f, 0.f};
            accQ[i][j] = (f32x4){0.f, 0.f, 0.f, 0.f};
        }
    #pragma unroll
    for (int kk = 0; kk < 2; ++kk) {
        uint32 cb = 64u * (uint32)kk + 16u * kq;
        short8 a0 = *(const short8*)(smem + swzb(LDS_FB, 16u * (uint32)(2 * wave + 0) + r16, cb));
        short8 a1 = *(const short8*)(smem + swzb(LDS_FB, 16u * (uint32)(2 * wave + 1) + r16, cb));
        #pragma unroll
        for (int tn = 0; tn < 4; ++tn) {
            short8 bt = *(const short8*)(smem + swzb(LDS_GHT, 16u * (uint32)tn + r16, cb));
            accT[0][tn] = MFMA(a0, bt, accT[0][tn]);
            accQ[0][tn] = MFMA(a0, qf[kk][tn], accQ[0][tn]);
            accT[1][tn] = MFMA(a1, bt, accT[1][tn]);
            accQ[1][tn] = MFMA(a1, qf[kk][tn], accQ[1][tn]);
        }
    }

    // ---- epilogue: out = F .* T + QF
    float* og = out + (size_t)b * 8192;
    #pragma unroll
    for (int i2 = 0; i2 < 2; ++i2)
        #pragma unroll
        for (int tn = 0; tn < 4; ++tn)
            #pragma unroll
            for (int r = 0; r < 4; ++r) {
                uint32 n = 16u * (uint32)(2 * wave + i2) + 4u * kq + (uint32)r;
                uint32 d = 16u * (uint32)tn + r16;
                float f = bf2f(*(const ushort_t*)(smem + swzb(LDS_FB, n, 2u * d)));
                og[n * 64 + d] = fmaf(f, accT[i2][tn][r], accQ[i2][tn][r]);
            }
}

extern "C" void kernel_launch(void* const* d_in, const int* in_sizes, int n_in,
                              void* d_out, int out_size, void* d_ws, size_t ws_size,
                              hipStream_t stream) {
    const float* F  = (const float*)d_in[0];
    const float* Kw = (const float*)d_in[1];
    const float* Qw = (const float*)d_in[2];
    float* out = (float*)d_out;
    int Bt = in_sizes[0] / (128 * 64);   // 4096
    sam3e_kernel<<<dim3(Bt), dim3(256), 0, stream>>>(F, Kw, Qw, out);
}

// Round 8
// 46.022 us; speedup vs baseline: 3.0832x; 1.1872x over previous
//
#include <hip/hip_runtime.h>

typedef __attribute__((ext_vector_type(8))) short short8;
typedef __attribute__((ext_vector_type(4))) short short4v;
typedef __attribute__((ext_vector_type(4))) float f32x4;
typedef unsigned int uint32;
typedef unsigned short ushort_t;

// LDS layout (bytes). All bf16 tiles, 128B row stride, XOR-swizzled. 40 KB.
#define LDS_FB   0u        // F   [128][64]
#define LDS_GHT  16384u    // G, then HT in-place [64][64]
#define LDS_KB   24576u    // Kw  [64][64] row-major
#define LDS_QB   32768u    // Qw  [64][64] row-major

__device__ __forceinline__ uint32 swzb(uint32 base, uint32 row, uint32 colByte) {
    return (base + row * 128u + colByte) ^ ((row & 7u) << 4);
}
__device__ __forceinline__ uint32 pk2(float lo, float hi) {   // v_cvt_pk_bf16_f32 (RNE)
    uint32 r;
    asm("v_cvt_pk_bf16_f32 %0, %1, %2" : "=v"(r) : "v"(lo), "v"(hi));
    return r;
}
__device__ __forceinline__ ushort_t bfbits(float x) {         // RNE f32 -> bf16 bits
    uint32 u = __float_as_uint(x);
    return (ushort_t)((u + 0x7FFFu + ((u >> 16) & 1u)) >> 16);
}
__device__ __forceinline__ float bf2f(ushort_t b) {
    return __uint_as_float(((uint32)b) << 16);
}
__device__ __forceinline__ short4v tr16(uint32 addr) {        // ds_read_b64_tr_b16
    short4v d;
    asm volatile("ds_read_b64_tr_b16 %0, %1" : "=v"(d) : "v"(addr));
    return d;
}
#define CAT8(lo, hi) __builtin_shufflevector(lo, hi, 0, 1, 2, 3, 4, 5, 6, 7)
#define MFMA(a, b, c) __builtin_amdgcn_mfma_f32_16x16x32_bf16((a), (b), (c), 0, 0, 0)
#define FENCE_LGKM0() do {                                                     \
    asm volatile("s_waitcnt lgkmcnt(0)" ::: "memory");                         \
    __builtin_amdgcn_sched_barrier(0);                                         \
} while (0)

__global__ __launch_bounds__(256, 4)
void sam3e_kernel(const float* __restrict__ F,
                  const float* __restrict__ Kw,
                  const float* __restrict__ Qw,
                  float* __restrict__ out) {
    __shared__ __align__(128) unsigned char smem[40960];
    const uint32 ldsb = (uint32)(size_t)(void*)smem;
    const int t    = threadIdx.x;
    const int lane = t & 63;
    const int wave = t >> 6;
    const int b    = blockIdx.x;
    const uint32 r16 = (uint32)(lane & 15);
    const uint32 kq  = (uint32)(lane >> 4);
    const uint32 trc = 8u * (r16 & 3u);
    const uint32 trr = r16 >> 2;

    // ---- stage F (batch b) -> bf16 LDS, row-major (HW cvt_pk)
    const float* Fg = F + (size_t)b * 8192;
    {
        int n0 = t >> 4;
        int c4 = (t & 15) * 4;
        #pragma unroll
        for (int i = 0; i < 8; ++i) {
            int n = n0 + 16 * i;
            float4 v = *(const float4*)(Fg + n * 64 + c4);
            uint2 pk; pk.x = pk2(v.x, v.y); pk.y = pk2(v.z, v.w);
            *(uint2*)(smem + swzb(LDS_FB, (uint32)n, (uint32)(2 * c4))) = pk;
        }
    }
    // ---- stage Kw, Qw -> bf16 LDS (coalesced float4 loads)
    #pragma unroll
    for (int i = 0; i < 4; ++i) {
        int idx4 = t + 256 * i;
        uint32 r = (uint32)(idx4 >> 4);
        uint32 cB = (uint32)((idx4 & 15) * 8);
        float4 vk = *(const float4*)(Kw + 4 * idx4);
        float4 vq = *(const float4*)(Qw + 4 * idx4);
        uint2 pk; pk.x = pk2(vk.x, vk.y); pk.y = pk2(vk.z, vk.w);
        uint2 pq; pq.x = pk2(vq.x, vq.y); pq.y = pk2(vq.z, vq.w);
        *(uint2*)(smem + swzb(LDS_KB, r, cB)) = pk;
        *(uint2*)(smem + swzb(LDS_QB, r, cB)) = pq;
    }
    __syncthreads();

    // ---- G = F^T F (64x64, K=128). Wave w: row band w x all col tiles.
    // A-fragment of band w == B-fragment of tile tn==w: reuse (8 tr16, not 10).
    f32x4 accG[4];
    #pragma unroll
    for (int i = 0; i < 4; ++i) accG[i] = (f32x4){0.f, 0.f, 0.f, 0.f};
    #pragma unroll
    for (int kk = 0; kk < 4; ++kk) {
        uint32 rA = (uint32)(32 * kk) + 8u * kq + trr;
        short4v b0l = tr16(ldsb + swzb(LDS_FB, rA,      0u  + trc));
        short4v b0h = tr16(ldsb + swzb(LDS_FB, rA + 4u, 0u  + trc));
        short4v b1l = tr16(ldsb + swzb(LDS_FB, rA,      32u + trc));
        short4v b1h = tr16(ldsb + swzb(LDS_FB, rA + 4u, 32u + trc));
        short4v b2l = tr16(ldsb + swzb(LDS_FB, rA,      64u + trc));
        short4v b2h = tr16(ldsb + swzb(LDS_FB, rA + 4u, 64u + trc));
        short4v b3l = tr16(ldsb + swzb(LDS_FB, rA,      96u + trc));
        short4v b3h = tr16(ldsb + swzb(LDS_FB, rA + 4u, 96u + trc));
        FENCE_LGKM0();
        short4v sal = wave == 0 ? b0l : wave == 1 ? b1l : wave == 2 ? b2l : b3l;
        short4v sah = wave == 0 ? b0h : wave == 1 ? b1h : wave == 2 ? b2h : b3h;
        short8 a = CAT8(sal, sah);
        accG[0] = MFMA(a, CAT8(b0l, b0h), accG[0]);
        accG[1] = MFMA(a, CAT8(b1l, b1h), accG[1]);
        accG[2] = MFMA(a, CAT8(b2l, b2h), accG[2]);
        accG[3] = MFMA(a, CAT8(b3l, b3h), accG[3]);
    }
    // write G band w (wave-local rows: only this wave reads them back)
    #pragma unroll
    for (int tn = 0; tn < 4; ++tn)
        #pragma unroll
        for (int r = 0; r < 4; ++r)
            *(ushort_t*)(smem + swzb(LDS_GHT, 16u * (uint32)wave + 4u * kq + (uint32)r,
                                     32u * (uint32)tn + 2u * r16)) = bfbits(accG[tn][r]);
    asm volatile("s_waitcnt lgkmcnt(0)" ::: "memory");  // wave-local RAW on GHT band
    __builtin_amdgcn_sched_barrier(0);

    // ---- HT = G @ Kw^T (64x64, K=64), band w in-place over G band w
    f32x4 accH[4];
    #pragma unroll
    for (int i = 0; i < 4; ++i) accH[i] = (f32x4){0.f, 0.f, 0.f, 0.f};
    #pragma unroll
    for (int kk = 0; kk < 2; ++kk) {
        uint32 cb = 64u * (uint32)kk + 16u * kq;
        short8 a = *(const short8*)(smem + swzb(LDS_GHT, 16u * (uint32)wave + r16, cb));
        #pragma unroll
        for (int tn = 0; tn < 4; ++tn) {
            short8 bb = *(const short8*)(smem + swzb(LDS_KB, 16u * (uint32)tn + r16, cb));
            accH[tn] = MFMA(a, bb, accH[tn]);
        }
    }
    asm volatile("" ::: "memory");  // keep HT stores below G reads
    #pragma unroll
    for (int tn = 0; tn < 4; ++tn)
        #pragma unroll
        for (int r = 0; r < 4; ++r)
            *(ushort_t*)(smem + swzb(LDS_GHT, 16u * (uint32)wave + 4u * kq + (uint32)r,
                                     32u * (uint32)tn + 2u * r16)) = bfbits(accH[tn][r]);
    __syncthreads();

    // ---- T = F @ H (B from HT rows), QF = F @ Qw^T (B from QB rows). 128x64, K=64.
    f32x4 accT[2][4], accQ[2][4];
    #pragma unroll
    for (int i = 0; i < 2; ++i)
        #pragma unroll
        for (int j = 0; j < 4; ++j) {
            accT[i][j] = (f32x4){0.f, 0.f, 0.f, 0.f};
            accQ[i][j] = (f32x4){0.f, 0.f, 0.f, 0.f};
        }
    __builtin_amdgcn_s_setprio(1);
    #pragma unroll
    for (int kk = 0; kk < 2; ++kk) {
        uint32 cb = 64u * (uint32)kk + 16u * kq;
        short8 a0 = *(const short8*)(smem + swzb(LDS_FB, 16u * (uint32)(2 * wave + 0) + r16, cb));
        short8 a1 = *(const short8*)(smem + swzb(LDS_FB, 16u * (uint32)(2 * wave + 1) + r16, cb));
        #pragma unroll
        for (int tn = 0; tn < 4; ++tn) {
            short8 bt = *(const short8*)(smem + swzb(LDS_GHT, 16u * (uint32)tn + r16, cb));
            short8 bq = *(const short8*)(smem + swzb(LDS_QB, 16u * (uint32)tn + r16, cb));
            accT[0][tn] = MFMA(a0, bt, accT[0][tn]);
            accQ[0][tn] = MFMA(a0, bq, accQ[0][tn]);
            accT[1][tn] = MFMA(a1, bt, accT[1][tn]);
            accQ[1][tn] = MFMA(a1, bq, accQ[1][tn]);
        }
    }
    __builtin_amdgcn_s_setprio(0);

    // ---- epilogue: out = F .* T + QF
    float* og = out + (size_t)b * 8192;
    #pragma unroll
    for (int i2 = 0; i2 < 2; ++i2)
        #pragma unroll
        for (int tn = 0; tn < 4; ++tn)
            #pragma unroll
            for (int r = 0; r < 4; ++r) {
                uint32 n = 16u * (uint32)(2 * wave + i2) + 4u * kq + (uint32)r;
                uint32 d = 16u * (uint32)tn + r16;
                float f = bf2f(*(const ushort_t*)(smem + swzb(LDS_FB, n, 2u * d)));
                og[n * 64 + d] = fmaf(f, accT[i2][tn][r], accQ[i2][tn][r]);
            }
}

extern "C" void kernel_launch(void* const* d_in, const int* in_sizes, int n_in,
                              void* d_out, int out_size, void* d_ws, size_t ws_size,
                              hipStream_t stream) {
    const float* F  = (const float*)d_in[0];
    const float* Kw = (const float*)d_in[1];
    const float* Qw = (const float*)d_in[2];
    float* out = (float*)d_out;
    int Bt = in_sizes[0] / (128 * 64);   // 4096
    sam3e_kernel<<<dim3(Bt), dim3(256), 0, stream>>>(F, Kw, Qw, out);
}